// Round 14
// baseline (436.870 us; speedup 1.0000x reference)
//
#include <hip/hip_runtime.h>

// ---------------- constants ----------------
#define S      4096
#define DM     1024
#define NB     4
#define NH     16
#define HDIM   64
#define MTOT   (NB * S)          // 16384
#define DS     ((long)DM * S)    // 4,194,304
#define MH     2304              // padded half-rows for Mc2 (2049 used)
#define KH     2112              // folded K for Mc2 (2049 used)
#define KH2    2112              // folded K for even/odd G split (2049 used)
#define MEO    2048              // even/odd GEMM rows (n=0..2047; n=2048 special)

typedef __attribute__((ext_vector_type(8))) short short8;
typedef __attribute__((ext_vector_type(4))) float f32x4;
typedef __attribute__((ext_vector_type(8))) unsigned short u16x8;
typedef __attribute__((ext_vector_type(4))) unsigned short u16x4;

__device__ __forceinline__ unsigned short f2bf(float f) {
  union { float f; unsigned u; } v; v.f = f;
  unsigned r = v.u + 0x7fffu + ((v.u >> 16) & 1u);   // RNE
  return (unsigned short)(r >> 16);
}
__device__ __forceinline__ float bf2f(short h) {
  union { unsigned u; float f; } v; v.u = ((unsigned)(unsigned short)h) << 16;
  return v.f;
}

#define GLOAD(gp, lp) __builtin_amdgcn_global_load_lds( \
    (const __attribute__((address_space(1))) void*)(gp), \
    (__attribute__((address_space(3))) void*)(lp), 16, 0, 0)

#define SBAR() do { asm volatile("" ::: "memory"); __builtin_amdgcn_s_barrier(); \
                    asm volatile("" ::: "memory"); } while (0)
#define WAITL0() asm volatile("s_waitcnt lgkmcnt(0)" ::: "memory")

// LDS swizzle for 64B-row tiles: XOR byte bits 4-5 with row bits 1-2 (byte bits 7-8).
#define SWZ(o) ((o) ^ ((((o) >> 7) & 3) << 4))

// ---------------- small kernels ----------------

// merged tables + g (block-local tables; identical fp formulas -> deterministic)
__global__ void k_tabg(const float* __restrict__ fd, const float* __restrict__ alpha,
                       const float* __restrict__ fsc,
                       float* __restrict__ cos_tab, float* __restrict__ c_arr,
                       float* __restrict__ g) {
  const float twopi = 6.28318530717958647692f;
  float aa = alpha[0] + fsc[0] * (fd[0] - 1.5f);
  int bx = blockIdx.x;
  if (bx < 16) {
    int k = bx * 256 + threadIdx.x;
    cos_tab[k] = cosf(twopi * ((float)k / (float)S));
    int kk = (k <= S / 2) ? k : (S - k);
    float af = (float)kk / (float)S;
    c_arr[k] = cosf(aa * atanf(logf(af + 1e-10f)));
    return;
  }
  __shared__ float sct[S];
  __shared__ float sc[S];
  __shared__ float red[16][17];
  for (int i = threadIdx.x; i < S; i += 256) {
    sct[i] = cosf(twopi * ((float)i / (float)S));
    int kk = (i <= S / 2) ? i : (S - i);
    float af = (float)kk / (float)S;
    sc[i] = cosf(aa * atanf(logf(af + 1e-10f)));
  }
  __syncthreads();
  int jl = threadIdx.x >> 4, r = threadIdx.x & 15;
  int j = (bx - 16) * 16 + jl;
  float acc = 0.f;
#pragma unroll 4
  for (int i = 0; i < 256; ++i) {
    int k = r + 16 * i;
    acc += sc[k] * sct[(j * k) & (S - 1)];
  }
  red[jl][r] = acc;
  __syncthreads();
  if (r == 0) {
    float s = 0.f;
#pragma unroll
    for (int i = 0; i < 16; ++i) s += red[jl][i];
    g[j] = s * (1.f / (float)S);
  }
}

// Ge/Go [MEO][KH2] bf16, Go at offset MEO*KH2.
__global__ void k_buildEO(const float* __restrict__ g, short* __restrict__ Ge) {
  long i8 = ((long)blockIdx.x * 256 + threadIdx.x) * 8;
  if (i8 >= (long)MEO * KH2) return;
  int n = (int)(i8 / KH2);
  int m = (int)(i8 % KH2);
  u16x8 ev, ov;
#pragma unroll
  for (int j = 0; j < 8; ++j) {
    int mm = m + j;
    float e, o;
    if (mm == 0)            { e = g[n]; o = 0.f; }
    else if (mm == 2048)    { e = g[(n + 2048) & (S - 1)]; o = 0.f; }
    else if (mm > 2048)     { e = 0.f; o = 0.f; }
    else {
      float a = g[(n - mm) & (S - 1)], b = g[(n + mm) & (S - 1)];
      e = 0.5f * (a + b); o = 0.5f * (a - b);
    }
    ev[j] = f2bf(e); ov[j] = f2bf(o);
  }
  *(u16x8*)(Ge + i8) = ev;
  *(u16x8*)(Ge + (long)MEO * KH2 + i8) = ov;
}

// merged foldT + transW4 (head-interleaved q/k rows) + interleaved qk bias.
// bx<33: fold x->uv; 33<=bx<49: transW tile; bx==49: biasI.
// Interleave: head h -> tile t=h>>1, half=h&1; q rows t*256+half*128+[0,64),
// k rows +64; V rows 2048+; Wo rows 3072+.
__global__ void k_prep(const float* __restrict__ x, short* __restrict__ uv,
                       const float* __restrict__ W0, const float* __restrict__ W1,
                       const float* __restrict__ W2, const float* __restrict__ W3,
                       short* __restrict__ WT,
                       const float* __restrict__ bq, const float* __restrict__ bk,
                       float* __restrict__ biasI) {
  __shared__ float sh[2 * 64 * 65];
  int bx = blockIdx.x, by = blockIdx.y, bz = blockIdx.z;
  int t = threadIdx.x;
  if (bx == 49) {
    if (bz != 0 || by >= 8) return;
    int o = by * 256 + t;                 // 0..2047
    int t2 = o >> 8, r2 = o & 255;
    int half = r2 >> 7, isK = (r2 >> 6) & 1, j = o & 63;
    int h = t2 * 2 + half;
    biasI[o] = (isK ? bk : bq)[h * 64 + j];
    return;
  }
  int r = t >> 4, c4 = (t & 15) * 4;
  if (bx >= 33) {
    float (*tile)[65] = (float(*)[65])sh;
    const float* W = (bz == 0) ? W0 : ((bz == 1) ? W1 : ((bz == 2) ? W2 : W3));
    long base_row;
    if (bz == 0)      base_row = (by >> 1) * 256 + (by & 1) * 128;
    else if (bz == 1) base_row = (by >> 1) * 256 + (by & 1) * 128 + 64;
    else if (bz == 2) base_row = 2048 + by * 64;
    else              base_row = 3072 + by * 64;
    int k0 = (bx - 33) * 64, n0 = by * 64;
    const float* ip = W + (long)k0 * DM + n0;
#pragma unroll
    for (int rr = 0; rr < 4; ++rr) {
      float4 v = *(const float4*)(ip + (long)(r + rr * 16) * DM + c4);
      tile[r + rr * 16][c4 + 0] = v.x;
      tile[r + rr * 16][c4 + 1] = v.y;
      tile[r + rr * 16][c4 + 2] = v.z;
      tile[r + rr * 16][c4 + 3] = v.w;
    }
    __syncthreads();
    int k_loc = t & 63, nq = t >> 6;
    short* op = WT + base_row * DM + k0;
#pragma unroll
    for (int i = 0; i < 16; ++i) {
      int n_loc = nq * 16 + i;
      op[(long)n_loc * DM + k_loc] = (short)f2bf(tile[k_loc][n_loc]);
    }
    return;
  }
  float (*tp)[65] = (float(*)[65])sh;
  float (*tm)[65] = (float(*)[65])(sh + 64 * 65);
  int m0 = bx * 64, d0 = by * 64, b = bz;
#pragma unroll
  for (int rr = 0; rr < 4; ++rr) {
    int m = m0 + r + rr * 16;
    float4 vp = *(const float4*)(x + ((long)(b * S + m)) * DM + d0 + c4);
    int ms = (S - m) & (S - 1);
    float4 vm = *(const float4*)(x + ((long)(b * S + ms)) * DM + d0 + c4);
    tp[r + rr * 16][c4 + 0] = vp.x; tp[r + rr * 16][c4 + 1] = vp.y;
    tp[r + rr * 16][c4 + 2] = vp.z; tp[r + rr * 16][c4 + 3] = vp.w;
    tm[r + rr * 16][c4 + 0] = vm.x; tm[r + rr * 16][c4 + 1] = vm.y;
    tm[r + rr * 16][c4 + 2] = vm.z; tm[r + rr * 16][c4 + 3] = vm.w;
  }
  __syncthreads();
  int m_loc = t & 63, dq = t >> 6;
#pragma unroll
  for (int i = 0; i < 16; ++i) {
    int d_loc = dq * 16 + i;
    int m = m0 + m_loc;
    float P = tp[m_loc][d_loc], M = tm[m_loc][d_loc];
    float u, v;
    if (m == 0 || m == 2048) { u = P; v = 0.f; }
    else if (m > 2048)       { u = 0.f; v = 0.f; }
    else                     { u = P + M; v = P - M; }
    long base = ((long)(b * DM + d0 + d_loc)) * KH2 + m;
    uv[base] = (short)f2bf(u);
    uv[base + (long)4 * DM * KH2] = (short)f2bf(v);
  }
}

// merged: blocks [0,4096): unfold AB -> Xs; blocks [4096,8192): row n=2048 dot
__global__ void k_unfold2(const short* __restrict__ AB, const float* __restrict__ g,
                          const short* __restrict__ uv, short* __restrict__ Xs) {
  __shared__ float red[256];
  int bx = blockIdx.x;
  if (bx < 4096) {
    long i8 = ((long)bx * 256 + threadIdx.x) * 8;
    int b = (int)(i8 >> 21);             // MEO*DM = 2^21
    long rr = i8 & ((1L << 21) - 1);
    int n = (int)(rr >> 10);
    int d = (int)(rr & (DM - 1));
    u16x8 av = *(const u16x8*)(AB + i8);
    u16x8 bv = *(const u16x8*)(AB + ((long)4 * MEO * DM) + i8);
    u16x8 sv, dv;
#pragma unroll
    for (int j = 0; j < 8; ++j) {
      float A = bf2f((short)av[j]), B = bf2f((short)bv[j]);
      sv[j] = f2bf(A + B);
      dv[j] = f2bf(A - B);
    }
    *(u16x8*)(Xs + ((long)b * S + n) * DM + d) = sv;
    if (n > 0)
      *(u16x8*)(Xs + ((long)b * S + (S - n)) * DM + d) = dv;
  } else {
    int bd = bx - 4096;                  // 0..NB*DM-1
    int b = bd >> 10, d = bd & (DM - 1);
    const short* up = uv + ((long)(b * DM + d)) * KH2;
    int t = threadIdx.x;
    float acc = 0.f;
    for (int m = t; m <= 2048; m += 256)
      acc += g[2048 - m] * bf2f(up[m]);
    red[t] = acc;
    __syncthreads();
    for (int sh = 128; sh > 0; sh >>= 1) {
      if (t < sh) red[t] += red[t + sh];
      __syncthreads();
    }
    if (t == 0) Xs[((long)b * S + 2048) * DM + d] = (short)f2bf(red[0]);
  }
}

// softmax over heads: logits[b][h][s] -> w[b][h][s]
__global__ void k_softw(const float* __restrict__ logits, float* __restrict__ w) {
  int idx = blockIdx.x * 256 + threadIdx.x;
  if (idx >= NB * S) return;
  int b = idx >> 12, s = idx & (S - 1);
  const float* lp = logits + (long)b * NH * S + s;
  float v[NH];
  float m = -1e30f;
#pragma unroll
  for (int h = 0; h < NH; ++h) { v[h] = lp[(long)h * S]; m = fmaxf(m, v[h]); }
  float sum = 0.f;
#pragma unroll
  for (int h = 0; h < NH; ++h) { v[h] = expf(v[h] - m); sum += v[h]; }
  float inv = 1.f / sum;
  float* wp = w + (long)b * NH * S + s;
#pragma unroll
  for (int h = 0; h < NH; ++h) wp[(long)h * S] = v[h] * inv;
}

// merged attfold2 + buildM2. bx<33: attend+fold tile; bx>=33: buildM2 chunk.
__global__ void k_attfoldM2(const short* __restrict__ V, const float* __restrict__ wsm,
                            short* __restrict__ A2t,
                            const float* __restrict__ cos_tab, short* __restrict__ Mc2) {
  int bx = blockIdx.x, by = blockIdx.y, bz = blockIdx.z;
  if (bx >= 33) {
    long lin = (long)(bx - 33) + 38L * (by + 16L * bz);   // 0..2431
    long i8 = (lin * 256 + threadIdx.x) * 8;
    if (i8 >= (long)MH * KH) return;
    int n = (int)(i8 / KH);
    int m = (int)(i8 % KH);
    u16x8 mv;
#pragma unroll
    for (int j = 0; j < 8; ++j) {
      int mm = m + j;
      float vv = (mm <= 2048) ? cos_tab[(n * mm) & (S - 1)] * 0.015625f : 0.f;
      mv[j] = f2bf(vv);
    }
    *(u16x8*)(Mc2 + i8) = mv;
    return;
  }
  __shared__ float t1[64][65];
  __shared__ float t2[64][65];
  __shared__ float w1[64], w2[64];
  int m0 = bx * 64, d0 = by * 64, b = bz;
  int t = threadIdx.x;
  int h0 = d0 >> 6;
  if (t < 64) {
    int m = m0 + t;
    const float* wp = wsm + ((long)b * NH + h0) * S;
    w1[t] = wp[m & (S - 1)];
    w2[t] = wp[(S - m) & (S - 1)];
  }
  int r = t >> 4, c4 = (t & 15) * 4;
#pragma unroll
  for (int rr = 0; rr < 4; ++rr) {
    int i = r + rr * 16;
    int m = m0 + i;
    u16x4 a = *(const u16x4*)(V + ((long)(b * S + (m & (S - 1)))) * DM + d0 + c4);
    u16x4 bb = *(const u16x4*)(V + ((long)(b * S + ((S - m) & (S - 1)))) * DM + d0 + c4);
#pragma unroll
    for (int l = 0; l < 4; ++l) {
      t1[i][c4 + l] = bf2f((short)a[l]);
      t2[i][c4 + l] = bf2f((short)bb[l]);
    }
  }
  __syncthreads();
  int i_loc = t & 63, jq = t >> 6;
  int m = m0 + i_loc;
#pragma unroll
  for (int jj = 0; jj < 16; ++jj) {
    int j = jq * 16 + jj;
    float rv;
    if (m == 0 || m == 2048) rv = w1[i_loc] * t1[i_loc][j];
    else if (m < 2048)       rv = w1[i_loc] * t1[i_loc][j] + w2[i_loc] * t2[i_loc][j];
    else                     rv = 0.f;
    A2t[((long)(b * DM + d0 + j)) * KH + m] = (short)f2bf(rv);
  }
}

// ---------------- 256x256 8-phase GEMM ----------------
// C = A @ B ; A row-major [M,K] bf16, B TRANSPOSED as Bt [N,K] bf16, ld = K.
// AMIR: A rows via even-symmetry mirror.  ASEL: A by bz>>2.  WALK/MREP as before.
// EPI 0: bf16 C[M,N] per-batch.  EPI 2: fp32 C + bias + resid.
// EPI 5: fused QKV. ntile<8 (interleaved q/k cols): stash acc+bias in LDS (bf16,
//        row-swizzled), per-thread 64-dot -> logits Cf[b][h][s]; Q,K never hit
//        HBM. ntile>=8: V write to Cb3 [row][col-2048] + bias3.
template <int EPI, int AMIR = 0, int ASEL = 0, int WALK = 0, int MREP = 1>
__global__ __launch_bounds__(512, 2) void gemm8(
    const short* __restrict__ A, const short* __restrict__ Bt,
    short* __restrict__ Cb, short* __restrict__ Cb2, short* __restrict__ Cb3,
    float* __restrict__ Cf,
    const float* __restrict__ bias, const float* __restrict__ bias2,
    const float* __restrict__ bias3,
    const float* __restrict__ bsc, const float* __restrict__ resid,
    int M, int N, int K, long aBatch, long bBatch, long cBatch) {
  __shared__ __align__(16) short SH[65536];   // 128 KiB
  auto Ab = [&](int buf, int ks) { return SH + (buf * 2 + ks) * 8192; };
  auto Bb = [&](int buf, int ks) { return SH + 32768 + (buf * 2 + ks) * 8192; };

  const int gx = gridDim.x, gy = gridDim.y;
  const int nwg = gx * gy * gridDim.z;
  int lin = blockIdx.x + gx * (blockIdx.y + gy * blockIdx.z);
  int swz = lin;
  if ((nwg & 7) == 0) {
    const int cpx = nwg >> 3;
    swz = (lin & 7) * cpx + (lin >> 3);
  }
  const int NTN = N >> 8;
  const int NTM = M >> 8;
  const int tid = threadIdx.x;
  const int lane = tid & 63;
  const int wid = tid >> 6;
  const int wm = wid >> 2, wn = wid & 3;

  const int o0 = tid * 16, o1 = o0 + 8192;
  const int lo0 = SWZ(o0), lo1 = SWZ(o1);
  const int srow[2] = {lo0 >> 6, lo1 >> 6};
  const int scol[2] = {(lo0 & 63) >> 1, (lo1 & 63) >> 1};

  for (int rep = 0; rep < MREP; ++rep) {
    const int wg = swz + rep * nwg;
    int ntile, mtile, bz;
    if (WALK) {
      mtile = wg % NTM;
      const int rest = wg / NTM;
      ntile = rest % NTN;
      bz = rest / NTN;
    } else {
      ntile = wg % NTN;
      const int rest = wg / NTN;
      mtile = rest % NTM;
      bz = rest / NTM;
    }

    const short* Ag = ASEL ? (A + (long)(bz >> 2) * aBatch) : (A + (long)bz * aBatch);
    const short* Bg = Bt + (long)bz * bBatch;
    const int m0 = mtile << 8, n0 = ntile << 8;

    const short* bA[2];
    const short* bB[2];
#pragma unroll
    for (int j = 0; j < 2; ++j) {
      if (AMIR) {
        int grow = m0 + srow[j];
        int b_ = grow >> 12, s_ = grow & (S - 1);
        int sm = (s_ <= 2048) ? s_ : (4096 - s_);
        bA[j] = Ag + ((long)b_ * MH + sm) * K + scol[j];
      } else {
        bA[j] = Ag + (long)(m0 + srow[j]) * K + scol[j];
      }
      bB[j] = Bg + (long)(n0 + srow[j]) * K + scol[j];
    }

    f32x4 acc[8][4];
#pragma unroll
    for (int i = 0; i < 8; ++i)
#pragma unroll
      for (int j = 0; j < 4; ++j) acc[i][j] = (f32x4){0.f, 0.f, 0.f, 0.f};

    const int NT = K >> 6;
    auto stage = [&](int h) {
      const int tau = h >> 2, q = h & 3;
      const int ks = q >> 1;
      const long k0 = (long)tau * 64 + ks * 32;
      const int dbase = (q & 1) * 65536 + (((tau & 1) << 1) + ks) * 16384;
      const short* b0 = (q & 1) ? bB[0] : bA[0];
      const short* b1 = (q & 1) ? bB[1] : bA[1];
      GLOAD(b0 + k0, (short*)((char*)SH + dbase + o0));
      GLOAD(b1 + k0, (short*)((char*)SH + dbase + o1));
    };

    if (rep > 0) SBAR();
#pragma unroll
    for (int h = 0; h < 7; ++h) stage(h);
    asm volatile("s_waitcnt vmcnt(6)" ::: "memory");
    SBAR();

    short8 bf[4];
    for (int t = 0; t < NT; ++t) {
      const int buf = t & 1;
#pragma unroll
      for (int p = 0; p < 4; ++p) {
        const int ks = p >> 1, mh = p & 1;
        short8 af[4];
        {
          const short* Ah = Ab(buf, ks);
          const int kb = (lane >> 4) * 16;
          const int r0 = wm * 128 + mh * 64 + (lane & 15);
#pragma unroll
          for (int i = 0; i < 4; ++i) {
            int byte = (r0 + i * 16) * 64 + kb;
            byte = SWZ(byte);
            af[i] = *(const short8*)((const char*)Ah + byte);
          }
          if (mh == 0) {
            const short* Bh = Bb(buf, ks);
            const int c0 = wn * 64 + (lane & 15);
#pragma unroll
            for (int j = 0; j < 4; ++j) {
              int byte = (c0 + j * 16) * 64 + kb;
              byte = SWZ(byte);
              bf[j] = *(const short8*)((const char*)Bh + byte);
            }
          }
        }
        { const int h = 4 * t + p + 7; if (h < 4 * NT) stage(h); }
        SBAR();
        WAITL0();
        __builtin_amdgcn_s_setprio(1);
#pragma unroll
        for (int i = 0; i < 4; ++i)
#pragma unroll
          for (int j = 0; j < 4; ++j)
            acc[mh * 4 + i][j] = __builtin_amdgcn_mfma_f32_16x16x32_bf16(
                af[i], bf[j], acc[mh * 4 + i][j], 0, 0, 0);
        __builtin_amdgcn_s_setprio(0);
        if (p == 3) {
          if (t < NT - 2) {
            asm volatile("s_waitcnt vmcnt(6)" ::: "memory");
          } else if (t == NT - 2) {
            asm volatile("s_waitcnt vmcnt(0)" ::: "memory");
          }
        }
        SBAR();
      }
    }

    const int rl = (lane >> 4) << 2;
    if constexpr (EPI == 5) {
      const float sc = bsc[0];
      if (ntile < 8) {
        // stash acc+bias as bf16 into SH [256 rows][256 cols], row-swizzled
#pragma unroll
        for (int f = 0; f < 8; ++f) {
          const int lr0 = wm * 128 + f * 16 + rl;
#pragma unroll
          for (int j = 0; j < 4; ++j) {
            const int lc = wn * 64 + j * 16 + (lane & 15);
            const float bi = bias[(ntile << 8) + lc] * sc;
            f32x4 a = acc[f][j];
#pragma unroll
            for (int r = 0; r < 4; ++r) {
              int row = lr0 + r;
              int ad = row * 512 + lc * 2;
              ad ^= (row & 7) << 4;
              *(short*)((char*)SH + ad) = (short)f2bf(a[r] + bi);
            }
          }
        }
        __syncthreads();
        // per-thread (row, head-pair-slot) 64-dim dot
        const int row = tid & 255, hp = tid >> 8;
        float dot = 0.f;
#pragma unroll
        for (int i = 0; i < 8; ++i) {
          int aq = row * 512 + hp * 256 + i * 16;       aq ^= (row & 7) << 4;
          int ak = row * 512 + hp * 256 + 128 + i * 16; ak ^= (row & 7) << 4;
          u16x8 qv = *(u16x8*)((char*)SH + aq);
          u16x8 kv = *(u16x8*)((char*)SH + ak);
#pragma unroll
          for (int l = 0; l < 8; ++l) dot += bf2f((short)qv[l]) * bf2f((short)kv[l]);
        }
        const int token = m0 + row;
        const int b_ = token >> 12, s_ = token & (S - 1);
        const int h = ntile * 2 + hp;
        Cf[((long)b_ * NH + h) * S + s_] = dot * 0.125f;
      } else {
        // V part: cols 2048..3071 -> Cb3 [row][dcol]
#pragma unroll
        for (int f = 0; f < 8; ++f) {
          const int rbase = m0 + wm * 128 + f * 16 + rl;
#pragma unroll
          for (int j = 0; j < 4; ++j) {
            const int col = n0 + wn * 64 + j * 16 + (lane & 15);
            const int dcol = col - 2048;
            const float bi = bias3[dcol] * sc;
            f32x4 a = acc[f][j];
#pragma unroll
            for (int r = 0; r < 4; ++r)
              Cb3[(long)(rbase + r) * DM + dcol] = (short)f2bf(a[r] + bi);
          }
        }
      }
    } else {
#pragma unroll
      for (int f = 0; f < 8; ++f) {
        const int rbase = m0 + wm * 128 + f * 16 + rl;
#pragma unroll
        for (int j = 0; j < 4; ++j) {
          const int col = n0 + wn * 64 + j * 16 + (lane & 15);
          f32x4 a = acc[f][j];
          if constexpr (EPI == 0) {
            short* cp = Cb + (long)bz * cBatch;
#pragma unroll
            for (int r = 0; r < 4; ++r)
              cp[(long)(rbase + r) * N + col] = (short)f2bf(a[r]);
          } else {
            float bi = bias[col];
#pragma unroll
            for (int r = 0; r < 4; ++r) {
              long o = (long)(rbase + r) * N + col;
              Cf[o] = a[r] + bi + resid[o];
            }
          }
        }
      }
    }
  }
}

// ---------------- launch ----------------
extern "C" void kernel_launch(void* const* d_in, const int* in_sizes, int n_in,
                              void* d_out, int out_size, void* d_ws, size_t ws_size,
                              hipStream_t stream) {
  const float* x     = (const float*)d_in[0];
  const float* fd    = (const float*)d_in[1];
  const float* Wq    = (const float*)d_in[2];
  const float* bq    = (const float*)d_in[3];
  const float* Wk    = (const float*)d_in[4];
  const float* bk    = (const float*)d_in[5];
  const float* Wv    = (const float*)d_in[6];
  const float* bv    = (const float*)d_in[7];
  const float* Wo    = (const float*)d_in[8];
  const float* bo    = (const float*)d_in[9];
  const float* alpha = (const float*)d_in[10];
  const float* fsc   = (const float*)d_in[11];
  float* out = (float*)d_out;

  // --- workspace layout (~113 MB) ---
  char* wp = (char*)d_ws;
  auto alloc = [&](size_t bytes) {
    char* p = wp;
    wp += (bytes + 255) & ~(size_t)255;
    return p;
  };
  float* cos_tab = (float*)alloc(S * 4);
  float* c_arr   = (float*)alloc(S * 4);          // c_arr[0] = c0 bias factor
  float* g       = (float*)alloc(S * 4);
  float* biasI   = (float*)alloc(2048 * 4);       // interleaved qk bias
  float* logits  = (float*)alloc((size_t)NB * NH * S * 4);   // 1 MB
  float* wsm     = (float*)alloc((size_t)NB * NH * S * 4);   // 1 MB
  short* WTcat = (short*)alloc((size_t)4 * DM * DM * 2);  // qk-interleaved + V + Wo
  short* WoT   = WTcat + (size_t)3 * DM * DM;
  short* slotA = (short*)alloc((size_t)NB * DS * 2);  // ABout -> V
  short* slotB = (short*)alloc((size_t)NB * DS * 2);  // Ge/Go -> Mc2 + A2t
  short* slotC = (short*)alloc((size_t)NB * DS * 2);  // Xs -> att_half

  short* uv = (short*)d_out;                        // [8][DM][KH2] scratch phase

  short* Ge  = slotB;
  short* ABout = slotA;
  short* Xs  = slotC;
  short* Vn  = slotA;
  short* Mc2 = slotB;
  short* A2t = (short*)((char*)slotB + 10u * 1024 * 1024);
  short* att_half = slotC;

  dim3 blk(256), blk8(512);

  // 1) tables+g  2) Ge/Go  3) fold x + interleaved weight transposes + biasI
  k_tabg<<<dim3(16 + S / 16), blk, 0, stream>>>(fd, alpha, fsc, cos_tab, c_arr, g);
  k_buildEO<<<dim3((unsigned)((long)MEO * KH2 / 8 / 256)), blk, 0, stream>>>(g, Ge);
  k_prep<<<dim3(50, 16, NB), blk, 0, stream>>>(x, uv, Wq, Wk, Wv, Wo, WTcat,
                                               bq, bk, biasI);

  // 4) even/odd spectral GEMM; 256 wg
  dim3 geo(DM / 256, MEO / 256, 8);
  gemm8<0, 0, 1><<<geo, blk8, 0, stream>>>(Ge, uv, ABout, nullptr, nullptr, nullptr,
                                           nullptr, nullptr, nullptr, nullptr, nullptr,
                                           MEO, DM, KH2,
                                           (long)MEO * KH2, (long)DM * KH2, (long)MEO * DM);
  // 5) unfold + row2048
  k_unfold2<<<dim3(8192), blk, 0, stream>>>(ABout, g, uv, Xs);

  // 6) fused QKV: q/k head-interleaved tiles -> logits in-epilogue; V -> Vn.
  gemm8<5, 0, 0, 0, 3><<<dim3(256), blk8, 0, stream>>>(
      Xs, WTcat, nullptr, nullptr, Vn, logits, biasI, nullptr, bv, c_arr, nullptr,
      MTOT, 3 * DM, DM, 0, 0, 0);

  // 7) head-softmax  8) attend+fold + buildM2
  k_softw<<<dim3(NB * S / 256), blk, 0, stream>>>(logits, wsm);
  k_attfoldM2<<<dim3(33 + 38, DM / 64, NB), blk, 0, stream>>>(Vn, wsm, A2t, cos_tab, Mc2);

  // 9) att_time_half = Mc2 @ A2
  dim3 ghalf(DM / 256, MH / 256, NB);
  gemm8<0><<<ghalf, blk8, 0, stream>>>(Mc2, A2t, att_half, nullptr, nullptr, nullptr,
                                       nullptr, nullptr, nullptr, nullptr, nullptr,
                                       MH, DM, KH, 0, (long)DM * KH, (long)MH * DM);

  // 10) out = att_time @ Wo + bo + x
  dim3 gproj(DM / 256, MTOT / 256, 1);
  gemm8<2, 1><<<gproj, blk8, 0, stream>>>(att_half, WoT, nullptr, nullptr, nullptr, out,
                                          bo, nullptr, nullptr, nullptr, x,
                                          MTOT, DM, DM, 0, 0, 0);
}

// Round 15
// 398.407 us; speedup vs baseline: 1.0965x; 1.0965x over previous
//
#include <hip/hip_runtime.h>

// ---------------- constants ----------------
#define S      4096
#define DM     1024
#define NB     4
#define NH     16
#define HDIM   64
#define MTOT   (NB * S)          // 16384
#define DS     ((long)DM * S)    // 4,194,304
#define MH     2304              // padded half-rows for Mc2 (2049 used)
#define KH     2112              // folded K for Mc2 (2049 used)
#define KH2    2112              // folded K for even/odd G split (2049 used)
#define MEO    2048              // even/odd GEMM rows (n=0..2047; n=2048 special)

typedef __attribute__((ext_vector_type(8))) short short8;
typedef __attribute__((ext_vector_type(4))) float f32x4;
typedef __attribute__((ext_vector_type(8))) unsigned short u16x8;
typedef __attribute__((ext_vector_type(4))) unsigned short u16x4;

__device__ __forceinline__ unsigned short f2bf(float f) {
  union { float f; unsigned u; } v; v.f = f;
  unsigned r = v.u + 0x7fffu + ((v.u >> 16) & 1u);   // RNE
  return (unsigned short)(r >> 16);
}
__device__ __forceinline__ float bf2f(short h) {
  union { unsigned u; float f; } v; v.u = ((unsigned)(unsigned short)h) << 16;
  return v.f;
}

#define GLOAD(gp, lp) __builtin_amdgcn_global_load_lds( \
    (const __attribute__((address_space(1))) void*)(gp), \
    (__attribute__((address_space(3))) void*)(lp), 16, 0, 0)

#define SBAR() do { asm volatile("" ::: "memory"); __builtin_amdgcn_s_barrier(); \
                    asm volatile("" ::: "memory"); } while (0)
#define WAITL0() asm volatile("s_waitcnt lgkmcnt(0)" ::: "memory")

// LDS swizzle for 64B-row tiles: XOR byte bits 4-5 with row bits 1-2 (byte bits 7-8).
#define SWZ(o) ((o) ^ ((((o) >> 7) & 3) << 4))

// ---------------- small kernels ----------------

// merged tables + g (block-local tables; identical fp formulas -> deterministic)
__global__ void k_tabg(const float* __restrict__ fd, const float* __restrict__ alpha,
                       const float* __restrict__ fsc,
                       float* __restrict__ cos_tab, float* __restrict__ c_arr,
                       float* __restrict__ g) {
  const float twopi = 6.28318530717958647692f;
  float aa = alpha[0] + fsc[0] * (fd[0] - 1.5f);
  int bx = blockIdx.x;
  if (bx < 16) {
    int k = bx * 256 + threadIdx.x;
    cos_tab[k] = cosf(twopi * ((float)k / (float)S));
    int kk = (k <= S / 2) ? k : (S - k);
    float af = (float)kk / (float)S;
    c_arr[k] = cosf(aa * atanf(logf(af + 1e-10f)));
    return;
  }
  __shared__ float sct[S];
  __shared__ float sc[S];
  __shared__ float red[16][17];
  for (int i = threadIdx.x; i < S; i += 256) {
    sct[i] = cosf(twopi * ((float)i / (float)S));
    int kk = (i <= S / 2) ? i : (S - i);
    float af = (float)kk / (float)S;
    sc[i] = cosf(aa * atanf(logf(af + 1e-10f)));
  }
  __syncthreads();
  int jl = threadIdx.x >> 4, r = threadIdx.x & 15;
  int j = (bx - 16) * 16 + jl;
  float acc = 0.f;
#pragma unroll 4
  for (int i = 0; i < 256; ++i) {
    int k = r + 16 * i;
    acc += sc[k] * sct[(j * k) & (S - 1)];
  }
  red[jl][r] = acc;
  __syncthreads();
  if (r == 0) {
    float s = 0.f;
#pragma unroll
    for (int i = 0; i < 16; ++i) s += red[jl][i];
    g[j] = s * (1.f / (float)S);
  }
}

// merged foldT + transW4 + buildEO.
// bx<33: fold x->uv tile; 33<=bx<49: transW tile; bx>=49: Ge/Go chunk.
__global__ void k_prep(const float* __restrict__ x, short* __restrict__ uv,
                       const float* __restrict__ W0, const float* __restrict__ W1,
                       const float* __restrict__ W2, const float* __restrict__ W3,
                       short* __restrict__ WT,
                       const float* __restrict__ g, short* __restrict__ Ge) {
  __shared__ float sh[2 * 64 * 65];
  int bx = blockIdx.x, by = blockIdx.y, bz = blockIdx.z;
  int t = threadIdx.x;
  if (bx >= 49) {
    // buildEO chunk
    long lin = (long)(bx - 49) + 54L * (by + 16L * bz);
    long i8 = (lin * 256 + t) * 8;
    if (i8 >= (long)MEO * KH2) return;
    int n = (int)(i8 / KH2);
    int m = (int)(i8 % KH2);
    u16x8 ev, ov;
#pragma unroll
    for (int j = 0; j < 8; ++j) {
      int mm = m + j;
      float e, o;
      if (mm == 0)            { e = g[n]; o = 0.f; }
      else if (mm == 2048)    { e = g[(n + 2048) & (S - 1)]; o = 0.f; }
      else if (mm > 2048)     { e = 0.f; o = 0.f; }
      else {
        float a = g[(n - mm) & (S - 1)], b = g[(n + mm) & (S - 1)];
        e = 0.5f * (a + b); o = 0.5f * (a - b);
      }
      ev[j] = f2bf(e); ov[j] = f2bf(o);
    }
    *(u16x8*)(Ge + i8) = ev;
    *(u16x8*)(Ge + (long)MEO * KH2 + i8) = ov;
    return;
  }
  int r = t >> 4, c4 = (t & 15) * 4;
  if (bx >= 33) {
    float (*tile)[65] = (float(*)[65])sh;
    const float* W = (bz == 0) ? W0 : ((bz == 1) ? W1 : ((bz == 2) ? W2 : W3));
    short* WTo = WT + (size_t)bz * DM * DM;
    int k0 = (bx - 33) * 64, n0 = by * 64;
    const float* ip = W + (long)k0 * DM + n0;
#pragma unroll
    for (int rr = 0; rr < 4; ++rr) {
      float4 v = *(const float4*)(ip + (long)(r + rr * 16) * DM + c4);
      tile[r + rr * 16][c4 + 0] = v.x;
      tile[r + rr * 16][c4 + 1] = v.y;
      tile[r + rr * 16][c4 + 2] = v.z;
      tile[r + rr * 16][c4 + 3] = v.w;
    }
    __syncthreads();
    int k_loc = t & 63, nq = t >> 6;
    short* op = WTo + (long)n0 * DM + k0;
#pragma unroll
    for (int i = 0; i < 16; ++i) {
      int n_loc = nq * 16 + i;
      op[(long)n_loc * DM + k_loc] = (short)f2bf(tile[k_loc][n_loc]);
    }
    return;
  }
  float (*tp)[65] = (float(*)[65])sh;
  float (*tm)[65] = (float(*)[65])(sh + 64 * 65);
  int m0 = bx * 64, d0 = by * 64, b = bz;
#pragma unroll
  for (int rr = 0; rr < 4; ++rr) {
    int m = m0 + r + rr * 16;
    float4 vp = *(const float4*)(x + ((long)(b * S + m)) * DM + d0 + c4);
    int ms = (S - m) & (S - 1);
    float4 vm = *(const float4*)(x + ((long)(b * S + ms)) * DM + d0 + c4);
    tp[r + rr * 16][c4 + 0] = vp.x; tp[r + rr * 16][c4 + 1] = vp.y;
    tp[r + rr * 16][c4 + 2] = vp.z; tp[r + rr * 16][c4 + 3] = vp.w;
    tm[r + rr * 16][c4 + 0] = vm.x; tm[r + rr * 16][c4 + 1] = vm.y;
    tm[r + rr * 16][c4 + 2] = vm.z; tm[r + rr * 16][c4 + 3] = vm.w;
  }
  __syncthreads();
  int m_loc = t & 63, dq = t >> 6;
#pragma unroll
  for (int i = 0; i < 16; ++i) {
    int d_loc = dq * 16 + i;
    int m = m0 + m_loc;
    float P = tp[m_loc][d_loc], M = tm[m_loc][d_loc];
    float u, v;
    if (m == 0 || m == 2048) { u = P; v = 0.f; }
    else if (m > 2048)       { u = 0.f; v = 0.f; }
    else                     { u = P + M; v = P - M; }
    long base = ((long)(b * DM + d0 + d_loc)) * KH2 + m;
    uv[base] = (short)f2bf(u);
    uv[base + (long)4 * DM * KH2] = (short)f2bf(v);
  }
}

// merged: blocks [0,4096): unfold AB -> Xs; blocks [4096,8192): row n=2048 dot
__global__ void k_unfold2(const short* __restrict__ AB, const float* __restrict__ g,
                          const short* __restrict__ uv, short* __restrict__ Xs) {
  __shared__ float red[256];
  int bx = blockIdx.x;
  if (bx < 4096) {
    long i8 = ((long)bx * 256 + threadIdx.x) * 8;
    int b = (int)(i8 >> 21);             // MEO*DM = 2^21
    long rr = i8 & ((1L << 21) - 1);
    int n = (int)(rr >> 10);
    int d = (int)(rr & (DM - 1));
    u16x8 av = *(const u16x8*)(AB + i8);
    u16x8 bv = *(const u16x8*)(AB + ((long)4 * MEO * DM) + i8);
    u16x8 sv, dv;
#pragma unroll
    for (int j = 0; j < 8; ++j) {
      float A = bf2f((short)av[j]), B = bf2f((short)bv[j]);
      sv[j] = f2bf(A + B);
      dv[j] = f2bf(A - B);
    }
    *(u16x8*)(Xs + ((long)b * S + n) * DM + d) = sv;
    if (n > 0)
      *(u16x8*)(Xs + ((long)b * S + (S - n)) * DM + d) = dv;
  } else {
    int bd = bx - 4096;                  // 0..NB*DM-1
    int b = bd >> 10, d = bd & (DM - 1);
    const short* up = uv + ((long)(b * DM + d)) * KH2;
    int t = threadIdx.x;
    float acc = 0.f;
    for (int m = t; m <= 2048; m += 256)
      acc += g[2048 - m] * bf2f(up[m]);
    red[t] = acc;
    __syncthreads();
    for (int sh = 128; sh > 0; sh >>= 1) {
      if (t < sh) red[t] += red[t + sh];
      __syncthreads();
    }
    if (t == 0) Xs[((long)b * S + 2048) * DM + d] = (short)f2bf(red[0]);
  }
}

// fused logits+head-softmax. Q,K in natural [(b,s)][DM] layout.
__global__ void k_logsoft(const short* __restrict__ Q, const short* __restrict__ K,
                          float* __restrict__ w) {
  int idx = blockIdx.x * 16 + (threadIdx.x >> 4);   // (b,s) 0..16383
  int h = threadIdx.x & 15;
  const short* q = Q + (long)idx * DM + h * HDIM;
  const short* k = K + (long)idx * DM + h * HDIM;
  float acc = 0.f;
#pragma unroll
  for (int jj = 0; jj < 8; ++jj) {
    u16x8 qa = *(const u16x8*)(q + jj * 8);
    u16x8 ka = *(const u16x8*)(k + jj * 8);
#pragma unroll
    for (int l = 0; l < 8; ++l) acc += bf2f((short)qa[l]) * bf2f((short)ka[l]);
  }
  acc *= 0.125f;
  float m = acc;
#pragma unroll
  for (int d = 1; d < 16; d <<= 1) m = fmaxf(m, __shfl_xor(m, d, 16));
  float e = expf(acc - m);
  float ssum = e;
#pragma unroll
  for (int d = 1; d < 16; d <<= 1) ssum += __shfl_xor(ssum, d, 16);
  int b = idx >> 12, s = idx & (S - 1);
  w[((long)b * NH + h) * S + s] = e / ssum;
}

// merged attfold2 + buildM2. bx<33: attend+fold tile; bx>=33: buildM2 chunk.
__global__ void k_attfoldM2(const short* __restrict__ V, const float* __restrict__ wsm,
                            short* __restrict__ A2t,
                            const float* __restrict__ cos_tab, short* __restrict__ Mc2) {
  int bx = blockIdx.x, by = blockIdx.y, bz = blockIdx.z;
  if (bx >= 33) {
    long lin = (long)(bx - 33) + 38L * (by + 16L * bz);   // 0..2431
    long i8 = (lin * 256 + threadIdx.x) * 8;
    if (i8 >= (long)MH * KH) return;
    int n = (int)(i8 / KH);
    int m = (int)(i8 % KH);
    u16x8 mv;
#pragma unroll
    for (int j = 0; j < 8; ++j) {
      int mm = m + j;
      float vv = (mm <= 2048) ? cos_tab[(n * mm) & (S - 1)] * 0.015625f : 0.f;
      mv[j] = f2bf(vv);
    }
    *(u16x8*)(Mc2 + i8) = mv;
    return;
  }
  __shared__ float t1[64][65];
  __shared__ float t2[64][65];
  __shared__ float w1[64], w2[64];
  int m0 = bx * 64, d0 = by * 64, b = bz;
  int t = threadIdx.x;
  int h0 = d0 >> 6;
  if (t < 64) {
    int m = m0 + t;
    const float* wp = wsm + ((long)b * NH + h0) * S;
    w1[t] = wp[m & (S - 1)];
    w2[t] = wp[(S - m) & (S - 1)];
  }
  int r = t >> 4, c4 = (t & 15) * 4;
#pragma unroll
  for (int rr = 0; rr < 4; ++rr) {
    int i = r + rr * 16;
    int m = m0 + i;
    u16x4 a = *(const u16x4*)(V + ((long)(b * S + (m & (S - 1)))) * DM + d0 + c4);
    u16x4 bb = *(const u16x4*)(V + ((long)(b * S + ((S - m) & (S - 1)))) * DM + d0 + c4);
#pragma unroll
    for (int l = 0; l < 4; ++l) {
      t1[i][c4 + l] = bf2f((short)a[l]);
      t2[i][c4 + l] = bf2f((short)bb[l]);
    }
  }
  __syncthreads();
  int i_loc = t & 63, jq = t >> 6;
  int m = m0 + i_loc;
#pragma unroll
  for (int jj = 0; jj < 16; ++jj) {
    int j = jq * 16 + jj;
    float rv;
    if (m == 0 || m == 2048) rv = w1[i_loc] * t1[i_loc][j];
    else if (m < 2048)       rv = w1[i_loc] * t1[i_loc][j] + w2[i_loc] * t2[i_loc][j];
    else                     rv = 0.f;
    A2t[((long)(b * DM + d0 + j)) * KH + m] = (short)f2bf(rv);
  }
}

// ---------------- 256x256 8-phase GEMM ----------------
// C = A @ B ; A row-major [M,K] bf16, B TRANSPOSED as Bt [N,K] bf16, ld = K.
// AMIR: A rows via even-symmetry mirror.  ASEL: A by bz>>2.  WALK: walk order.
// MREP>1 (with KNT = compile-time NT): persistent blocks, K-loops of all reps
// concatenated into one continuous pipeline (lookahead staging crosses rep
// boundaries; vmcnt(6) maintained; epilogues run with loads in flight).
// EPI 0: bf16 C[M,N] per-batch.  EPI 2: fp32 C + bias + resid.
// EPI 4: QKV natural layout — rows=(b,s), col=dout; Cb/Cb2/Cb3 by col>>10.
template <int EPI, int AMIR = 0, int ASEL = 0, int WALK = 0, int MREP = 1, int KNT = 0>
__global__ __launch_bounds__(512, 2) void gemm8(
    const short* __restrict__ A, const short* __restrict__ Bt,
    short* __restrict__ Cb, short* __restrict__ Cb2, short* __restrict__ Cb3,
    float* __restrict__ Cf,
    const float* __restrict__ bias, const float* __restrict__ bias2,
    const float* __restrict__ bias3,
    const float* __restrict__ bsc, const float* __restrict__ resid,
    int M, int N, int K, long aBatch, long bBatch, long cBatch) {
  __shared__ __align__(16) short SH[65536];   // 128 KiB
  auto Ab = [&](int buf, int ks) { return SH + (buf * 2 + ks) * 8192; };
  auto Bb = [&](int buf, int ks) { return SH + 32768 + (buf * 2 + ks) * 8192; };

  const int gx = gridDim.x, gy = gridDim.y;
  const int nwg = gx * gy * gridDim.z;
  int lin = blockIdx.x + gx * (blockIdx.y + gy * blockIdx.z);
  int swz = lin;
  if ((nwg & 7) == 0) {
    const int cpx = nwg >> 3;
    swz = (lin & 7) * cpx + (lin >> 3);
  }
  const int NTN = N >> 8;
  const int NTM = M >> 8;
  const int tid = threadIdx.x;
  const int lane = tid & 63;
  const int wid = tid >> 6;
  const int wm = wid >> 2, wn = wid & 3;

  const int o0 = tid * 16, o1 = o0 + 8192;
  const int lo0 = SWZ(o0), lo1 = SWZ(o1);
  const int srow[2] = {lo0 >> 6, lo1 >> 6};
  const int scol[2] = {(lo0 & 63) >> 1, (lo1 & 63) >> 1};

  auto decode = [&](int wg, int& mt, int& nt2, int& bzz) {
    if (WALK) {
      mt = wg % NTM;
      const int rest = wg / NTM;
      nt2 = rest % NTN;
      bzz = rest / NTN;
    } else {
      nt2 = wg % NTN;
      const int rest = wg / NTN;
      mt = rest % NTM;
      bzz = rest / NTM;
    }
  };

  // ---- phase body macro pieces (shared between branches) ----
  auto ldsReads = [&](int buf, int ks, int mh, short8 af[4], short8 bf[4]) {
    const short* Ah = Ab(buf, ks);
    const int kb = (lane >> 4) * 16;
    const int r0 = wm * 128 + mh * 64 + (lane & 15);
#pragma unroll
    for (int i = 0; i < 4; ++i) {
      int byte = (r0 + i * 16) * 64 + kb;
      byte = SWZ(byte);
      af[i] = *(const short8*)((const char*)Ah + byte);
    }
    if (mh == 0) {
      const short* Bh = Bb(buf, ks);
      const int c0 = wn * 64 + (lane & 15);
#pragma unroll
      for (int j = 0; j < 4; ++j) {
        int byte = (c0 + j * 16) * 64 + kb;
        byte = SWZ(byte);
        bf[j] = *(const short8*)((const char*)Bh + byte);
      }
    }
  };

  if constexpr (MREP > 1) {
    // ---------- continuous cross-rep pipeline ----------
    constexpr int LNT = (KNT == 16) ? 4 : ((KNT == 32) ? 5 : 6);
    const int TOT = KNT * MREP;
    int mt_[2], nt_[2];
    const short* bA_[2][2];
    const short* bB_[2][2];
    auto setSlot = [&](int r) {
      const int slot = r & 1;
      int mt, nt2, bzz;
      decode(swz + r * nwg, mt, nt2, bzz);
      mt_[slot] = mt; nt_[slot] = nt2;
      const short* Ag = ASEL ? (A + (long)(bzz >> 2) * aBatch) : (A + (long)bzz * aBatch);
      const short* Bg = Bt + (long)bzz * bBatch;
      const int m0 = mt << 8, n0 = nt2 << 8;
#pragma unroll
      for (int j = 0; j < 2; ++j) {
        if (AMIR) {
          int grow = m0 + srow[j];
          int b_ = grow >> 12, s_ = grow & (S - 1);
          int sm = (s_ <= 2048) ? s_ : (4096 - s_);
          bA_[slot][j] = Ag + ((long)b_ * MH + sm) * K + scol[j];
        } else {
          bA_[slot][j] = Ag + (long)(m0 + srow[j]) * K + scol[j];
        }
        bB_[slot][j] = Bg + (long)(n0 + srow[j]) * K + scol[j];
      }
    };
    setSlot(0);
    setSlot(1);

    auto stageG = [&](int H) {
      const int tau = H >> 2, q = H & 3, ks = q >> 1;
      const int slot = (tau >> LNT) & 1;
      const int lt = tau & (KNT - 1);
      const long k0 = (long)lt * 64 + ks * 32;
      const int dbase = (q & 1) * 65536 + (((tau & 1) << 1) + ks) * 16384;
      const short* b0 = (q & 1) ? bB_[slot][0] : bA_[slot][0];
      const short* b1 = (q & 1) ? bB_[slot][1] : bA_[slot][1];
      GLOAD(b0 + k0, (short*)((char*)SH + dbase + o0));
      GLOAD(b1 + k0, (short*)((char*)SH + dbase + o1));
    };

#pragma unroll
    for (int h = 0; h < 7; ++h) stageG(h);
    asm volatile("s_waitcnt vmcnt(6)" ::: "memory");
    SBAR();

    for (int rep = 0; rep < MREP; ++rep) {
      if (rep >= 1 && rep + 1 < MREP) setSlot(rep + 1);
      f32x4 acc[8][4];
#pragma unroll
      for (int i = 0; i < 8; ++i)
#pragma unroll
        for (int j = 0; j < 4; ++j) acc[i][j] = (f32x4){0.f, 0.f, 0.f, 0.f};

      short8 bf[4];
      for (int t = 0; t < KNT; ++t) {
        const int gt = rep * KNT + t;
        const int buf = gt & 1;
#pragma unroll
        for (int p = 0; p < 4; ++p) {
          const int ks = p >> 1, mh = p & 1;
          short8 af[4];
          ldsReads(buf, ks, mh, af, bf);
          { const int H = 4 * gt + p + 7; if (H < 4 * TOT) stageG(H); }
          SBAR();
          WAITL0();
          __builtin_amdgcn_s_setprio(1);
#pragma unroll
          for (int i = 0; i < 4; ++i)
#pragma unroll
            for (int j = 0; j < 4; ++j)
              acc[mh * 4 + i][j] = __builtin_amdgcn_mfma_f32_16x16x32_bf16(
                  af[i], bf[j], acc[mh * 4 + i][j], 0, 0, 0);
          __builtin_amdgcn_s_setprio(0);
          if (p == 3) {
            if (gt < TOT - 2) {
              asm volatile("s_waitcnt vmcnt(6)" ::: "memory");
            } else if (gt == TOT - 2) {
              asm volatile("s_waitcnt vmcnt(0)" ::: "memory");
            }
          }
          SBAR();
        }
      }

      // epilogue (runs with next-rep loads still in flight; no LDS touched)
      const int m0 = mt_[rep & 1] << 8, n0 = nt_[rep & 1] << 8;
      const int rl = (lane >> 4) << 2;
      const float sc = bsc ? bsc[0] : 1.f;
#pragma unroll
      for (int f = 0; f < 8; ++f) {
        const int rbase = m0 + wm * 128 + f * 16 + rl;
#pragma unroll
        for (int j = 0; j < 4; ++j) {
          const int col = n0 + wn * 64 + j * 16 + (lane & 15);
          f32x4 a = acc[f][j];
          // EPI == 4 only in this branch
          const int pidx = col >> 10;
          const int dcol = col & (DM - 1);
          short* Cp = (pidx == 0) ? Cb : ((pidx == 1) ? Cb2 : Cb3);
          const float* bp = (pidx == 0) ? bias : ((pidx == 1) ? bias2 : bias3);
          const float bi = bp[dcol] * sc;
#pragma unroll
          for (int r = 0; r < 4; ++r)
            Cp[(long)(rbase + r) * DM + dcol] = (short)f2bf(a[r] + bi);
        }
      }
    }
    return;
  }

  // ---------- single-rep path (R13-proven) ----------
  {
    int ntile, mtile, bz;
    decode(swz, mtile, ntile, bz);

    const short* Ag = ASEL ? (A + (long)(bz >> 2) * aBatch) : (A + (long)bz * aBatch);
    const short* Bg = Bt + (long)bz * bBatch;
    const int m0 = mtile << 8, n0 = ntile << 8;

    const short* bA[2];
    const short* bB[2];
#pragma unroll
    for (int j = 0; j < 2; ++j) {
      if (AMIR) {
        int grow = m0 + srow[j];
        int b_ = grow >> 12, s_ = grow & (S - 1);
        int sm = (s_ <= 2048) ? s_ : (4096 - s_);
        bA[j] = Ag + ((long)b_ * MH + sm) * K + scol[j];
      } else {
        bA[j] = Ag + (long)(m0 + srow[j]) * K + scol[j];
      }
      bB[j] = Bg + (long)(n0 + srow[j]) * K + scol[j];
    }

    f32x4 acc[8][4];
#pragma unroll
    for (int i = 0; i < 8; ++i)
#pragma unroll
      for (int j = 0; j < 4; ++j) acc[i][j] = (f32x4){0.f, 0.f, 0.f, 0.f};

    const int NT = K >> 6;
    auto stage = [&](int h) {
      const int tau = h >> 2, q = h & 3;
      const int ks = q >> 1;
      const long k0 = (long)tau * 64 + ks * 32;
      const int dbase = (q & 1) * 65536 + (((tau & 1) << 1) + ks) * 16384;
      const short* b0 = (q & 1) ? bB[0] : bA[0];
      const short* b1 = (q & 1) ? bB[1] : bA[1];
      GLOAD(b0 + k0, (short*)((char*)SH + dbase + o0));
      GLOAD(b1 + k0, (short*)((char*)SH + dbase + o1));
    };

#pragma unroll
    for (int h = 0; h < 7; ++h) stage(h);
    asm volatile("s_waitcnt vmcnt(6)" ::: "memory");
    SBAR();

    short8 bf[4];
    for (int t = 0; t < NT; ++t) {
      const int buf = t & 1;
#pragma unroll
      for (int p = 0; p < 4; ++p) {
        const int ks = p >> 1, mh = p & 1;
        short8 af[4];
        ldsReads(buf, ks, mh, af, bf);
        { const int h = 4 * t + p + 7; if (h < 4 * NT) stage(h); }
        SBAR();
        WAITL0();
        __builtin_amdgcn_s_setprio(1);
#pragma unroll
        for (int i = 0; i < 4; ++i)
#pragma unroll
          for (int j = 0; j < 4; ++j)
            acc[mh * 4 + i][j] = __builtin_amdgcn_mfma_f32_16x16x32_bf16(
                af[i], bf[j], acc[mh * 4 + i][j], 0, 0, 0);
        __builtin_amdgcn_s_setprio(0);
        if (p == 3) {
          if (t < NT - 2) {
            asm volatile("s_waitcnt vmcnt(6)" ::: "memory");
          } else if (t == NT - 2) {
            asm volatile("s_waitcnt vmcnt(0)" ::: "memory");
          }
        }
        SBAR();
      }
    }

    const int rl = (lane >> 4) << 2;
#pragma unroll
    for (int f = 0; f < 8; ++f) {
      const int rbase = m0 + wm * 128 + f * 16 + rl;
#pragma unroll
      for (int j = 0; j < 4; ++j) {
        const int col = n0 + wn * 64 + j * 16 + (lane & 15);
        f32x4 a = acc[f][j];
        if constexpr (EPI == 0) {
          short* cp = Cb + (long)bz * cBatch;
#pragma unroll
          for (int r = 0; r < 4; ++r)
            cp[(long)(rbase + r) * N + col] = (short)f2bf(a[r]);
        } else if constexpr (EPI == 4) {
          const int pidx = col >> 10;
          const int dcol = col & (DM - 1);
          short* Cp = (pidx == 0) ? Cb : ((pidx == 1) ? Cb2 : Cb3);
          const float* bp = (pidx == 0) ? bias : ((pidx == 1) ? bias2 : bias3);
          const float bi = bp[dcol] * (bsc ? bsc[0] : 1.f);
#pragma unroll
          for (int r = 0; r < 4; ++r)
            Cp[(long)(rbase + r) * DM + dcol] = (short)f2bf(a[r] + bi);
        } else {
          float bi = bias[col];
#pragma unroll
          for (int r = 0; r < 4; ++r) {
            long o = (long)(rbase + r) * N + col;
            Cf[o] = a[r] + bi + resid[o];
          }
        }
      }
    }
  }
}

// ---------------- launch ----------------
extern "C" void kernel_launch(void* const* d_in, const int* in_sizes, int n_in,
                              void* d_out, int out_size, void* d_ws, size_t ws_size,
                              hipStream_t stream) {
  const float* x     = (const float*)d_in[0];
  const float* fd    = (const float*)d_in[1];
  const float* Wq    = (const float*)d_in[2];
  const float* bq    = (const float*)d_in[3];
  const float* Wk    = (const float*)d_in[4];
  const float* bk    = (const float*)d_in[5];
  const float* Wv    = (const float*)d_in[6];
  const float* bv    = (const float*)d_in[7];
  const float* Wo    = (const float*)d_in[8];
  const float* bo    = (const float*)d_in[9];
  const float* alpha = (const float*)d_in[10];
  const float* fsc   = (const float*)d_in[11];
  float* out = (float*)d_out;

  // --- workspace layout (~112 MB) ---
  char* wp = (char*)d_ws;
  auto alloc = [&](size_t bytes) {
    char* p = wp;
    wp += (bytes + 255) & ~(size_t)255;
    return p;
  };
  float* cos_tab = (float*)alloc(S * 4);
  float* c_arr   = (float*)alloc(S * 4);          // c_arr[0] = c0 bias factor
  float* g       = (float*)alloc(S * 4);
  float* wsm     = (float*)alloc((size_t)NB * NH * S * 4);   // 1 MB
  short* WTcat = (short*)alloc((size_t)4 * DM * DM * 2);  // Wq,Wk,Wv,Wo transposed
  short* WoT   = WTcat + (size_t)3 * DM * DM;
  short* slotA = (short*)alloc((size_t)NB * DS * 2);  // ABout -> V
  short* slotB = (short*)alloc((size_t)NB * DS * 2);  // Ge/Go -> Mc2 + A2t
  short* slotC = (short*)alloc((size_t)NB * DS * 2);  // Xs -> att_half

  // d_out scratch phases: uv (34.6MB) during G-phase; Q,K during attention
  short* uv = (short*)d_out;                        // [8][DM][KH2]
  short* Qn = (short*)d_out;                        // [(b,s)][DM] 33.5 MB
  short* Kn = (short*)d_out + (size_t)NB * DS;      // [(b,s)][DM] 33.5 MB

  short* Ge  = slotB;                               // [2][MEO][KH2] (Ge,Go)
  short* ABout = slotA;                             // [8][MEO][DM]
  short* Xs  = slotC;
  short* Vn  = slotA;                               // V natural (after ABout dead)
  short* Mc2 = slotB;                               // 9.73 MB (after Ge dead)
  short* A2t = (short*)((char*)slotB + 10u * 1024 * 1024);
  short* att_half = slotC;

  dim3 blk(256), blk8(512);

  // 1) tables+g   2) fold x + weight transposes + Ge/Go (merged)
  k_tabg<<<dim3(16 + S / 16), blk, 0, stream>>>(fd, alpha, fsc, cos_tab, c_arr, g);
  k_prep<<<dim3(49 + 54, 16, NB), blk, 0, stream>>>(x, uv, Wq, Wk, Wv, Wo, WTcat, g, Ge);

  // 3) even/odd spectral GEMM: AB[z] = (z<4 ? Ge : Go) @ uv[z]; 256 wg
  dim3 geo(DM / 256, MEO / 256, 8);
  gemm8<0, 0, 1><<<geo, blk8, 0, stream>>>(Ge, uv, ABout, nullptr, nullptr, nullptr,
                                           nullptr, nullptr, nullptr, nullptr, nullptr,
                                           MEO, DM, KH2,
                                           (long)MEO * KH2, (long)DM * KH2, (long)MEO * DM);
  // 4) unfold mirror + row n=2048 into Xs [b][s][d]
  k_unfold2<<<dim3(8192), blk, 0, stream>>>(ABout, g, uv, Xs);

  // 5) fused q/k/v projections (EPI=4), persistent 256 blocks x 3 tiles with a
  //    continuous cross-rep pipeline (KNT=16 compile-time K-tiles per rep)
  gemm8<4, 0, 0, 0, 3, 16><<<dim3(256), blk8, 0, stream>>>(
      Xs, WTcat, Qn, Kn, Vn, nullptr, bq, bk, bv, c_arr, nullptr,
      MTOT, 3 * DM, DM, 0, 0, 0);

  // 6) fused logits + head-softmax   7) attend+fold + buildM2 (merged)
  k_logsoft<<<dim3(MTOT / 16), blk, 0, stream>>>(Qn, Kn, wsm);
  k_attfoldM2<<<dim3(33 + 38, DM / 64, NB), blk, 0, stream>>>(Vn, wsm, A2t, cos_tab, Mc2);

  // 8) att_time_half = Mc2 @ A2
  dim3 ghalf(DM / 256, MH / 256, NB);
  gemm8<0><<<ghalf, blk8, 0, stream>>>(Mc2, A2t, att_half, nullptr, nullptr, nullptr,
                                       nullptr, nullptr, nullptr, nullptr, nullptr,
                                       MH, DM, KH, 0, (long)DM * KH, (long)MH * DM);

  // 9) out = att_time @ Wo + bo + x
  dim3 gproj(DM / 256, MTOT / 256, 1);
  gemm8<2, 1><<<gproj, blk8, 0, stream>>>(att_half, WoT, nullptr, nullptr, nullptr, out,
                                          bo, nullptr, nullptr, nullptr, x,
                                          MTOT, DM, DM, 0, 0, 0);
}

// Round 16
// 386.573 us; speedup vs baseline: 1.1301x; 1.0306x over previous
//
#include <hip/hip_runtime.h>

// ---------------- constants ----------------
#define S      4096
#define DM     1024
#define NB     4
#define NH     16
#define HDIM   64
#define MTOT   (NB * S)          // 16384
#define DS     ((long)DM * S)    // 4,194,304
#define MH     2304              // padded half-rows for Mc2 (2049 used)
#define KH     2112              // folded K for Mc2 (2049 used)
#define KH2    2112              // folded K for even/odd G split (2049 used)
#define MEO    2048              // even/odd GEMM rows (n=0..2047; n=2048 special)

typedef __attribute__((ext_vector_type(8))) short short8;
typedef __attribute__((ext_vector_type(4))) float f32x4;
typedef __attribute__((ext_vector_type(8))) unsigned short u16x8;
typedef __attribute__((ext_vector_type(4))) unsigned short u16x4;

__device__ __forceinline__ unsigned short f2bf(float f) {
  union { float f; unsigned u; } v; v.f = f;
  unsigned r = v.u + 0x7fffu + ((v.u >> 16) & 1u);   // RNE
  return (unsigned short)(r >> 16);
}
__device__ __forceinline__ float bf2f(short h) {
  union { unsigned u; float f; } v; v.u = ((unsigned)(unsigned short)h) << 16;
  return v.f;
}

#define GLOAD(gp, lp) __builtin_amdgcn_global_load_lds( \
    (const __attribute__((address_space(1))) void*)(gp), \
    (__attribute__((address_space(3))) void*)(lp), 16, 0, 0)

#define SBAR() do { asm volatile("" ::: "memory"); __builtin_amdgcn_s_barrier(); \
                    asm volatile("" ::: "memory"); } while (0)
#define WAITL0() asm volatile("s_waitcnt lgkmcnt(0)" ::: "memory")

// LDS swizzle for 64B-row tiles: XOR byte bits 4-5 with row bits 1-2 (byte bits 7-8).
#define SWZ(o) ((o) ^ ((((o) >> 7) & 3) << 4))

// ---------------- small kernels ----------------

// merged tables + g (block-local tables; identical fp formulas -> deterministic)
__global__ void k_tabg(const float* __restrict__ fd, const float* __restrict__ alpha,
                       const float* __restrict__ fsc,
                       float* __restrict__ cos_tab, float* __restrict__ c_arr,
                       float* __restrict__ g) {
  const float twopi = 6.28318530717958647692f;
  float aa = alpha[0] + fsc[0] * (fd[0] - 1.5f);
  int bx = blockIdx.x;
  if (bx < 16) {
    int k = bx * 256 + threadIdx.x;
    cos_tab[k] = cosf(twopi * ((float)k / (float)S));
    int kk = (k <= S / 2) ? k : (S - k);
    float af = (float)kk / (float)S;
    c_arr[k] = cosf(aa * atanf(logf(af + 1e-10f)));
    return;
  }
  __shared__ float sct[S];
  __shared__ float sc[S];
  __shared__ float red[16][17];
  for (int i = threadIdx.x; i < S; i += 256) {
    sct[i] = cosf(twopi * ((float)i / (float)S));
    int kk = (i <= S / 2) ? i : (S - i);
    float af = (float)kk / (float)S;
    sc[i] = cosf(aa * atanf(logf(af + 1e-10f)));
  }
  __syncthreads();
  int jl = threadIdx.x >> 4, r = threadIdx.x & 15;
  int j = (bx - 16) * 16 + jl;
  float acc = 0.f;
#pragma unroll 4
  for (int i = 0; i < 256; ++i) {
    int k = r + 16 * i;
    acc += sc[k] * sct[(j * k) & (S - 1)];
  }
  red[jl][r] = acc;
  __syncthreads();
  if (r == 0) {
    float s = 0.f;
#pragma unroll
    for (int i = 0; i < 16; ++i) s += red[jl][i];
    g[j] = s * (1.f / (float)S);
  }
}

// merged foldT + transW4 + buildEO.
// bx<33: fold x->uv tile; 33<=bx<49: transW tile; bx>=49: Ge/Go chunk.
__global__ void k_prep(const float* __restrict__ x, short* __restrict__ uv,
                       const float* __restrict__ W0, const float* __restrict__ W1,
                       const float* __restrict__ W2, const float* __restrict__ W3,
                       short* __restrict__ WT,
                       const float* __restrict__ g, short* __restrict__ Ge) {
  __shared__ float sh[2 * 64 * 65];
  int bx = blockIdx.x, by = blockIdx.y, bz = blockIdx.z;
  int t = threadIdx.x;
  if (bx >= 49) {
    long lin = (long)(bx - 49) + 54L * (by + 16L * bz);
    long i8 = (lin * 256 + t) * 8;
    if (i8 >= (long)MEO * KH2) return;
    int n = (int)(i8 / KH2);
    int m = (int)(i8 % KH2);
    u16x8 ev, ov;
#pragma unroll
    for (int j = 0; j < 8; ++j) {
      int mm = m + j;
      float e, o;
      if (mm == 0)            { e = g[n]; o = 0.f; }
      else if (mm == 2048)    { e = g[(n + 2048) & (S - 1)]; o = 0.f; }
      else if (mm > 2048)     { e = 0.f; o = 0.f; }
      else {
        float a = g[(n - mm) & (S - 1)], b = g[(n + mm) & (S - 1)];
        e = 0.5f * (a + b); o = 0.5f * (a - b);
      }
      ev[j] = f2bf(e); ov[j] = f2bf(o);
    }
    *(u16x8*)(Ge + i8) = ev;
    *(u16x8*)(Ge + (long)MEO * KH2 + i8) = ov;
    return;
  }
  int r = t >> 4, c4 = (t & 15) * 4;
  if (bx >= 33) {
    float (*tile)[65] = (float(*)[65])sh;
    const float* W = (bz == 0) ? W0 : ((bz == 1) ? W1 : ((bz == 2) ? W2 : W3));
    short* WTo = WT + (size_t)bz * DM * DM;
    int k0 = (bx - 33) * 64, n0 = by * 64;
    const float* ip = W + (long)k0 * DM + n0;
#pragma unroll
    for (int rr = 0; rr < 4; ++rr) {
      float4 v = *(const float4*)(ip + (long)(r + rr * 16) * DM + c4);
      tile[r + rr * 16][c4 + 0] = v.x;
      tile[r + rr * 16][c4 + 1] = v.y;
      tile[r + rr * 16][c4 + 2] = v.z;
      tile[r + rr * 16][c4 + 3] = v.w;
    }
    __syncthreads();
    int k_loc = t & 63, nq = t >> 6;
    short* op = WTo + (long)n0 * DM + k0;
#pragma unroll
    for (int i = 0; i < 16; ++i) {
      int n_loc = nq * 16 + i;
      op[(long)n_loc * DM + k_loc] = (short)f2bf(tile[k_loc][n_loc]);
    }
    return;
  }
  float (*tp)[65] = (float(*)[65])sh;
  float (*tm)[65] = (float(*)[65])(sh + 64 * 65);
  int m0 = bx * 64, d0 = by * 64, b = bz;
#pragma unroll
  for (int rr = 0; rr < 4; ++rr) {
    int m = m0 + r + rr * 16;
    float4 vp = *(const float4*)(x + ((long)(b * S + m)) * DM + d0 + c4);
    int ms = (S - m) & (S - 1);
    float4 vm = *(const float4*)(x + ((long)(b * S + ms)) * DM + d0 + c4);
    tp[r + rr * 16][c4 + 0] = vp.x; tp[r + rr * 16][c4 + 1] = vp.y;
    tp[r + rr * 16][c4 + 2] = vp.z; tp[r + rr * 16][c4 + 3] = vp.w;
    tm[r + rr * 16][c4 + 0] = vm.x; tm[r + rr * 16][c4 + 1] = vm.y;
    tm[r + rr * 16][c4 + 2] = vm.z; tm[r + rr * 16][c4 + 3] = vm.w;
  }
  __syncthreads();
  int m_loc = t & 63, dq = t >> 6;
#pragma unroll
  for (int i = 0; i < 16; ++i) {
    int d_loc = dq * 16 + i;
    int m = m0 + m_loc;
    float P = tp[m_loc][d_loc], M = tm[m_loc][d_loc];
    float u, v;
    if (m == 0 || m == 2048) { u = P; v = 0.f; }
    else if (m > 2048)       { u = 0.f; v = 0.f; }
    else                     { u = P + M; v = P - M; }
    long base = ((long)(b * DM + d0 + d_loc)) * KH2 + m;
    uv[base] = (short)f2bf(u);
    uv[base + (long)4 * DM * KH2] = (short)f2bf(v);
  }
}

// merged: blocks [0,4096): unfold AB -> Xs; blocks [4096,8192): row n=2048 dot
__global__ void k_unfold2(const short* __restrict__ AB, const float* __restrict__ g,
                          const short* __restrict__ uv, short* __restrict__ Xs) {
  __shared__ float red[256];
  int bx = blockIdx.x;
  if (bx < 4096) {
    long i8 = ((long)bx * 256 + threadIdx.x) * 8;
    int b = (int)(i8 >> 21);             // MEO*DM = 2^21
    long rr = i8 & ((1L << 21) - 1);
    int n = (int)(rr >> 10);
    int d = (int)(rr & (DM - 1));
    u16x8 av = *(const u16x8*)(AB + i8);
    u16x8 bv = *(const u16x8*)(AB + ((long)4 * MEO * DM) + i8);
    u16x8 sv, dv;
#pragma unroll
    for (int j = 0; j < 8; ++j) {
      float A = bf2f((short)av[j]), B = bf2f((short)bv[j]);
      sv[j] = f2bf(A + B);
      dv[j] = f2bf(A - B);
    }
    *(u16x8*)(Xs + ((long)b * S + n) * DM + d) = sv;
    if (n > 0)
      *(u16x8*)(Xs + ((long)b * S + (S - n)) * DM + d) = dv;
  } else {
    int bd = bx - 4096;                  // 0..NB*DM-1
    int b = bd >> 10, d = bd & (DM - 1);
    const short* up = uv + ((long)(b * DM + d)) * KH2;
    int t = threadIdx.x;
    float acc = 0.f;
    for (int m = t; m <= 2048; m += 256)
      acc += g[2048 - m] * bf2f(up[m]);
    red[t] = acc;
    __syncthreads();
    for (int sh = 128; sh > 0; sh >>= 1) {
      if (t < sh) red[t] += red[t + sh];
      __syncthreads();
    }
    if (t == 0) Xs[((long)b * S + 2048) * DM + d] = (short)f2bf(red[0]);
  }
}

// fused logits+head-softmax. Q,K in natural [(b,s)][DM] layout.
__global__ void k_logsoft(const short* __restrict__ Q, const short* __restrict__ K,
                          float* __restrict__ w) {
  int idx = blockIdx.x * 16 + (threadIdx.x >> 4);   // (b,s) 0..16383
  int h = threadIdx.x & 15;
  const short* q = Q + (long)idx * DM + h * HDIM;
  const short* k = K + (long)idx * DM + h * HDIM;
  float acc = 0.f;
#pragma unroll
  for (int jj = 0; jj < 8; ++jj) {
    u16x8 qa = *(const u16x8*)(q + jj * 8);
    u16x8 ka = *(const u16x8*)(k + jj * 8);
#pragma unroll
    for (int l = 0; l < 8; ++l) acc += bf2f((short)qa[l]) * bf2f((short)ka[l]);
  }
  acc *= 0.125f;
  float m = acc;
#pragma unroll
  for (int d = 1; d < 16; d <<= 1) m = fmaxf(m, __shfl_xor(m, d, 16));
  float e = expf(acc - m);
  float ssum = e;
#pragma unroll
  for (int d = 1; d < 16; d <<= 1) ssum += __shfl_xor(ssum, d, 16);
  int b = idx >> 12, s = idx & (S - 1);
  w[((long)b * NH + h) * S + s] = e / ssum;
}

// merged attfold2 + buildM2. bx<33: attend+fold tile; bx>=33: buildM2 chunk.
__global__ void k_attfoldM2(const short* __restrict__ V, const float* __restrict__ wsm,
                            short* __restrict__ A2t,
                            const float* __restrict__ cos_tab, short* __restrict__ Mc2) {
  int bx = blockIdx.x, by = blockIdx.y, bz = blockIdx.z;
  if (bx >= 33) {
    long lin = (long)(bx - 33) + 38L * (by + 16L * bz);   // 0..2431
    long i8 = (lin * 256 + threadIdx.x) * 8;
    if (i8 >= (long)MH * KH) return;
    int n = (int)(i8 / KH);
    int m = (int)(i8 % KH);
    u16x8 mv;
#pragma unroll
    for (int j = 0; j < 8; ++j) {
      int mm = m + j;
      float vv = (mm <= 2048) ? cos_tab[(n * mm) & (S - 1)] * 0.015625f : 0.f;
      mv[j] = f2bf(vv);
    }
    *(u16x8*)(Mc2 + i8) = mv;
    return;
  }
  __shared__ float t1[64][65];
  __shared__ float t2[64][65];
  __shared__ float w1[64], w2[64];
  int m0 = bx * 64, d0 = by * 64, b = bz;
  int t = threadIdx.x;
  int h0 = d0 >> 6;
  if (t < 64) {
    int m = m0 + t;
    const float* wp = wsm + ((long)b * NH + h0) * S;
    w1[t] = wp[m & (S - 1)];
    w2[t] = wp[(S - m) & (S - 1)];
  }
  int r = t >> 4, c4 = (t & 15) * 4;
#pragma unroll
  for (int rr = 0; rr < 4; ++rr) {
    int i = r + rr * 16;
    int m = m0 + i;
    u16x4 a = *(const u16x4*)(V + ((long)(b * S + (m & (S - 1)))) * DM + d0 + c4);
    u16x4 bb = *(const u16x4*)(V + ((long)(b * S + ((S - m) & (S - 1)))) * DM + d0 + c4);
#pragma unroll
    for (int l = 0; l < 4; ++l) {
      t1[i][c4 + l] = bf2f((short)a[l]);
      t2[i][c4 + l] = bf2f((short)bb[l]);
    }
  }
  __syncthreads();
  int i_loc = t & 63, jq = t >> 6;
  int m = m0 + i_loc;
#pragma unroll
  for (int jj = 0; jj < 16; ++jj) {
    int j = jq * 16 + jj;
    float rv;
    if (m == 0 || m == 2048) rv = w1[i_loc] * t1[i_loc][j];
    else if (m < 2048)       rv = w1[i_loc] * t1[i_loc][j] + w2[i_loc] * t2[i_loc][j];
    else                     rv = 0.f;
    A2t[((long)(b * DM + d0 + j)) * KH + m] = (short)f2bf(rv);
  }
}

// ---------------- 256x256 8-phase GEMM (R13-proven) ----------------
template <int EPI, int AMIR = 0, int ASEL = 0, int WALK = 0, int MREP = 1>
__global__ __launch_bounds__(512, 2) void gemm8(
    const short* __restrict__ A, const short* __restrict__ Bt,
    short* __restrict__ Cb, short* __restrict__ Cb2, short* __restrict__ Cb3,
    float* __restrict__ Cf,
    const float* __restrict__ bias, const float* __restrict__ bias2,
    const float* __restrict__ bias3,
    const float* __restrict__ bsc, const float* __restrict__ resid,
    int M, int N, int K, long aBatch, long bBatch, long cBatch) {
  __shared__ __align__(16) short SH[65536];   // 128 KiB
  auto Ab = [&](int buf, int ks) { return SH + (buf * 2 + ks) * 8192; };
  auto Bb = [&](int buf, int ks) { return SH + 32768 + (buf * 2 + ks) * 8192; };

  const int gx = gridDim.x, gy = gridDim.y;
  const int nwg = gx * gy * gridDim.z;
  int lin = blockIdx.x + gx * (blockIdx.y + gy * blockIdx.z);
  int swz = lin;
  if ((nwg & 7) == 0) {
    const int cpx = nwg >> 3;
    swz = (lin & 7) * cpx + (lin >> 3);
  }
  const int NTN = N >> 8;
  const int NTM = M >> 8;
  const int tid = threadIdx.x;
  const int lane = tid & 63;
  const int wid = tid >> 6;
  const int wm = wid >> 2, wn = wid & 3;

  const int o0 = tid * 16, o1 = o0 + 8192;
  const int lo0 = SWZ(o0), lo1 = SWZ(o1);
  const int srow[2] = {lo0 >> 6, lo1 >> 6};
  const int scol[2] = {(lo0 & 63) >> 1, (lo1 & 63) >> 1};

  for (int rep = 0; rep < MREP; ++rep) {
    const int wg = swz + rep * nwg;
    int ntile, mtile, bz;
    if (WALK) {
      mtile = wg % NTM;
      const int rest = wg / NTM;
      ntile = rest % NTN;
      bz = rest / NTN;
    } else {
      ntile = wg % NTN;
      const int rest = wg / NTN;
      mtile = rest % NTM;
      bz = rest / NTM;
    }

    const short* Ag = ASEL ? (A + (long)(bz >> 2) * aBatch) : (A + (long)bz * aBatch);
    const short* Bg = Bt + (long)bz * bBatch;
    const int m0 = mtile << 8, n0 = ntile << 8;

    const short* bA[2];
    const short* bB[2];
#pragma unroll
    for (int j = 0; j < 2; ++j) {
      if (AMIR) {
        int grow = m0 + srow[j];
        int b_ = grow >> 12, s_ = grow & (S - 1);
        int sm = (s_ <= 2048) ? s_ : (4096 - s_);
        bA[j] = Ag + ((long)b_ * MH + sm) * K + scol[j];
      } else {
        bA[j] = Ag + (long)(m0 + srow[j]) * K + scol[j];
      }
      bB[j] = Bg + (long)(n0 + srow[j]) * K + scol[j];
    }

    f32x4 acc[8][4];
#pragma unroll
    for (int i = 0; i < 8; ++i)
#pragma unroll
      for (int j = 0; j < 4; ++j) acc[i][j] = (f32x4){0.f, 0.f, 0.f, 0.f};

    const int NT = K >> 6;
    auto stage = [&](int h) {
      const int tau = h >> 2, q = h & 3;
      const int ks = q >> 1;
      const long k0 = (long)tau * 64 + ks * 32;
      const int dbase = (q & 1) * 65536 + (((tau & 1) << 1) + ks) * 16384;
      const short* b0 = (q & 1) ? bB[0] : bA[0];
      const short* b1 = (q & 1) ? bB[1] : bA[1];
      GLOAD(b0 + k0, (short*)((char*)SH + dbase + o0));
      GLOAD(b1 + k0, (short*)((char*)SH + dbase + o1));
    };

    if (rep > 0) SBAR();
#pragma unroll
    for (int h = 0; h < 7; ++h) stage(h);
    asm volatile("s_waitcnt vmcnt(6)" ::: "memory");
    SBAR();

    short8 bf[4];
    for (int t = 0; t < NT; ++t) {
      const int buf = t & 1;
#pragma unroll
      for (int p = 0; p < 4; ++p) {
        const int ks = p >> 1, mh = p & 1;
        short8 af[4];
        {
          const short* Ah = Ab(buf, ks);
          const int kb = (lane >> 4) * 16;
          const int r0 = wm * 128 + mh * 64 + (lane & 15);
#pragma unroll
          for (int i = 0; i < 4; ++i) {
            int byte = (r0 + i * 16) * 64 + kb;
            byte = SWZ(byte);
            af[i] = *(const short8*)((const char*)Ah + byte);
          }
          if (mh == 0) {
            const short* Bh = Bb(buf, ks);
            const int c0 = wn * 64 + (lane & 15);
#pragma unroll
            for (int j = 0; j < 4; ++j) {
              int byte = (c0 + j * 16) * 64 + kb;
              byte = SWZ(byte);
              bf[j] = *(const short8*)((const char*)Bh + byte);
            }
          }
        }
        { const int h = 4 * t + p + 7; if (h < 4 * NT) stage(h); }
        SBAR();
        WAITL0();
        __builtin_amdgcn_s_setprio(1);
#pragma unroll
        for (int i = 0; i < 4; ++i)
#pragma unroll
          for (int j = 0; j < 4; ++j)
            acc[mh * 4 + i][j] = __builtin_amdgcn_mfma_f32_16x16x32_bf16(
                af[i], bf[j], acc[mh * 4 + i][j], 0, 0, 0);
        __builtin_amdgcn_s_setprio(0);
        if (p == 3) {
          if (t < NT - 2) {
            asm volatile("s_waitcnt vmcnt(6)" ::: "memory");
          } else if (t == NT - 2) {
            asm volatile("s_waitcnt vmcnt(0)" ::: "memory");
          }
        }
        SBAR();
      }
    }

    const int rl = (lane >> 4) << 2;
#pragma unroll
    for (int f = 0; f < 8; ++f) {
      const int rbase = m0 + wm * 128 + f * 16 + rl;
#pragma unroll
      for (int j = 0; j < 4; ++j) {
        const int col = n0 + wn * 64 + j * 16 + (lane & 15);
        f32x4 a = acc[f][j];
        if constexpr (EPI == 0) {
          short* cp = Cb + (long)bz * cBatch;
#pragma unroll
          for (int r = 0; r < 4; ++r)
            cp[(long)(rbase + r) * N + col] = (short)f2bf(a[r]);
        } else if constexpr (EPI == 4) {
          const int pidx = col >> 10;
          const int dcol = col & (DM - 1);
          short* Cp = (pidx == 0) ? Cb : ((pidx == 1) ? Cb2 : Cb3);
          const float* bp = (pidx == 0) ? bias : ((pidx == 1) ? bias2 : bias3);
          const float bi = bp[dcol] * (bsc ? bsc[0] : 1.f);
#pragma unroll
          for (int r = 0; r < 4; ++r)
            Cp[(long)(rbase + r) * DM + dcol] = (short)f2bf(a[r] + bi);
        } else {
          float bi = bias[col];
#pragma unroll
          for (int r = 0; r < 4; ++r) {
            long o = (long)(rbase + r) * N + col;
            Cf[o] = a[r] + bi + resid[o];
          }
        }
      }
    }
  }
}

// ---------------- 128x128 4-wave GEMM (same schedule, higher occupancy) ----------
// C = A @ B bf16; A [M,K] shared across batch, Bt [N,K] batched, C batched.
// 256 threads = 4 waves (2m x 2n), per-wave 64x64, acc[4][4], 8 MFMA/phase.
// LDS 64 KiB -> 2 blocks/CU. Staging: 8 loads/K-tile (2 per half), same vmcnt(6).
__global__ __launch_bounds__(256, 2) void gemm4(
    const short* __restrict__ A, const short* __restrict__ Bt,
    short* __restrict__ Cb,
    int M, int N, int K, long bBatch, long cBatch) {
  __shared__ __align__(16) short SH[32768];   // 64 KiB: A 4x8KB then B 4x8KB
  auto Ab = [&](int buf, int ks) { return SH + (buf * 2 + ks) * 4096; };
  auto Bb = [&](int buf, int ks) { return SH + 16384 + (buf * 2 + ks) * 4096; };

  const int gx = gridDim.x, gy = gridDim.y;
  const int nwg = gx * gy * gridDim.z;
  int lin = blockIdx.x + gx * (blockIdx.y + gy * blockIdx.z);
  int swz = lin;
  if ((nwg & 7) == 0) {
    const int cpx = nwg >> 3;
    swz = (lin & 7) * cpx + (lin >> 3);
  }
  const int NTN = N >> 7;
  const int NTM = M >> 7;
  const int ntile = swz % NTN;
  const int rest = swz / NTN;
  const int mtile = rest % NTM;
  const int bz = rest / NTM;

  const short* Ag = A;
  const short* Bg = Bt + (long)bz * bBatch;
  const int m0 = mtile << 7, n0 = ntile << 7;
  const int tid = threadIdx.x;
  const int lane = tid & 63;
  const int wid = tid >> 6;
  const int wm = wid >> 1, wn = wid & 1;

  const int o0 = tid * 16, o1 = o0 + 4096;
  const int lo0 = SWZ(o0), lo1 = SWZ(o1);
  const int srow[2] = {lo0 >> 6, lo1 >> 6};
  const int scol[2] = {(lo0 & 63) >> 1, (lo1 & 63) >> 1};

  const short* bA[2];
  const short* bB[2];
#pragma unroll
  for (int j = 0; j < 2; ++j) {
    bA[j] = Ag + (long)(m0 + srow[j]) * K + scol[j];
    bB[j] = Bg + (long)(n0 + srow[j]) * K + scol[j];
  }

  f32x4 acc[4][4];
#pragma unroll
  for (int i = 0; i < 4; ++i)
#pragma unroll
    for (int j = 0; j < 4; ++j) acc[i][j] = (f32x4){0.f, 0.f, 0.f, 0.f};

  const int NT = K >> 6;
  auto stage = [&](int h) {
    const int tau = h >> 2, q = h & 3;
    const int ks = q >> 1;
    const long k0 = (long)tau * 64 + ks * 32;
    const int dbase = (q & 1) * 32768 + (((tau & 1) << 1) + ks) * 8192;
    const short* b0 = (q & 1) ? bB[0] : bA[0];
    const short* b1 = (q & 1) ? bB[1] : bA[1];
    GLOAD(b0 + k0, (short*)((char*)SH + dbase + o0));
    GLOAD(b1 + k0, (short*)((char*)SH + dbase + o1));
  };

#pragma unroll
  for (int h = 0; h < 7; ++h) stage(h);
  asm volatile("s_waitcnt vmcnt(6)" ::: "memory");
  SBAR();

  short8 bf[4];
  for (int t = 0; t < NT; ++t) {
    const int buf = t & 1;
#pragma unroll
    for (int p = 0; p < 4; ++p) {
      const int ks = p >> 1, mh = p & 1;
      short8 af[2];
      {
        const short* Ah = Ab(buf, ks);
        const int kb = (lane >> 4) * 16;
        const int r0 = wm * 64 + mh * 32 + (lane & 15);
#pragma unroll
        for (int i = 0; i < 2; ++i) {
          int byte = (r0 + i * 16) * 64 + kb;
          byte = SWZ(byte);
          af[i] = *(const short8*)((const char*)Ah + byte);
        }
        if (mh == 0) {
          const short* Bh = Bb(buf, ks);
          const int c0 = wn * 64 + (lane & 15);
#pragma unroll
          for (int j = 0; j < 4; ++j) {
            int byte = (c0 + j * 16) * 64 + kb;
            byte = SWZ(byte);
            bf[j] = *(const short8*)((const char*)Bh + byte);
          }
        }
      }
      { const int h = 4 * t + p + 7; if (h < 4 * NT) stage(h); }
      SBAR();
      WAITL0();
      __builtin_amdgcn_s_setprio(1);
#pragma unroll
      for (int i = 0; i < 2; ++i)
#pragma unroll
        for (int j = 0; j < 4; ++j)
          acc[mh * 2 + i][j] = __builtin_amdgcn_mfma_f32_16x16x32_bf16(
              af[i], bf[j], acc[mh * 2 + i][j], 0, 0, 0);
      __builtin_amdgcn_s_setprio(0);
      if (p == 3) {
        if (t < NT - 2) {
          asm volatile("s_waitcnt vmcnt(6)" ::: "memory");
        } else if (t == NT - 2) {
          asm volatile("s_waitcnt vmcnt(0)" ::: "memory");
        }
      }
      SBAR();
    }
  }

  const int rl = (lane >> 4) << 2;
  short* cp = Cb + (long)bz * cBatch;
#pragma unroll
  for (int f = 0; f < 4; ++f) {
    const int rbase = m0 + wm * 64 + f * 16 + rl;
#pragma unroll
    for (int j = 0; j < 4; ++j) {
      const int col = n0 + wn * 64 + j * 16 + (lane & 15);
      f32x4 a = acc[f][j];
#pragma unroll
      for (int r = 0; r < 4; ++r)
        cp[(long)(rbase + r) * N + col] = (short)f2bf(a[r]);
    }
  }
}

// ---------------- launch ----------------
extern "C" void kernel_launch(void* const* d_in, const int* in_sizes, int n_in,
                              void* d_out, int out_size, void* d_ws, size_t ws_size,
                              hipStream_t stream) {
  const float* x     = (const float*)d_in[0];
  const float* fd    = (const float*)d_in[1];
  const float* Wq    = (const float*)d_in[2];
  const float* bq    = (const float*)d_in[3];
  const float* Wk    = (const float*)d_in[4];
  const float* bk    = (const float*)d_in[5];
  const float* Wv    = (const float*)d_in[6];
  const float* bv    = (const float*)d_in[7];
  const float* Wo    = (const float*)d_in[8];
  const float* bo    = (const float*)d_in[9];
  const float* alpha = (const float*)d_in[10];
  const float* fsc   = (const float*)d_in[11];
  float* out = (float*)d_out;

  // --- workspace layout (~112 MB) ---
  char* wp = (char*)d_ws;
  auto alloc = [&](size_t bytes) {
    char* p = wp;
    wp += (bytes + 255) & ~(size_t)255;
    return p;
  };
  float* cos_tab = (float*)alloc(S * 4);
  float* c_arr   = (float*)alloc(S * 4);          // c_arr[0] = c0 bias factor
  float* g       = (float*)alloc(S * 4);
  float* wsm     = (float*)alloc((size_t)NB * NH * S * 4);   // 1 MB
  short* WTcat = (short*)alloc((size_t)4 * DM * DM * 2);  // Wq,Wk,Wv,Wo transposed
  short* WoT   = WTcat + (size_t)3 * DM * DM;
  short* slotA = (short*)alloc((size_t)NB * DS * 2);  // ABout -> V
  short* slotB = (short*)alloc((size_t)NB * DS * 2);  // Ge/Go -> Mc2 + A2t
  short* slotC = (short*)alloc((size_t)NB * DS * 2);  // Xs -> att_half

  // d_out scratch phases: uv (34.6MB) during G-phase; Q,K during attention
  short* uv = (short*)d_out;                        // [8][DM][KH2]
  short* Qn = (short*)d_out;                        // [(b,s)][DM] 33.5 MB
  short* Kn = (short*)d_out + (size_t)NB * DS;      // [(b,s)][DM] 33.5 MB

  short* Ge  = slotB;                               // [2][MEO][KH2] (Ge,Go)
  short* ABout = slotA;                             // [8][MEO][DM]
  short* Xs  = slotC;
  short* Vn  = slotA;                               // V natural (after ABout dead)
  short* Mc2 = slotB;                               // 9.73 MB (after Ge dead)
  short* A2t = (short*)((char*)slotB + 10u * 1024 * 1024);
  short* att_half = slotC;

  dim3 blk(256), blk8(512);

  // 1) tables+g   2) fold x + weight transposes + Ge/Go (merged)
  k_tabg<<<dim3(16 + S / 16), blk, 0, stream>>>(fd, alpha, fsc, cos_tab, c_arr, g);
  k_prep<<<dim3(49 + 54, 16, NB), blk, 0, stream>>>(x, uv, Wq, Wk, Wv, Wo, WTcat, g, Ge);

  // 3) even/odd spectral GEMM: AB[z] = (z<4 ? Ge : Go) @ uv[z]; 256 wg
  dim3 geo(DM / 256, MEO / 256, 8);
  gemm8<0, 0, 1><<<geo, blk8, 0, stream>>>(Ge, uv, ABout, nullptr, nullptr, nullptr,
                                           nullptr, nullptr, nullptr, nullptr, nullptr,
                                           MEO, DM, KH2,
                                           (long)MEO * KH2, (long)DM * KH2, (long)MEO * DM);
  // 4) unfold mirror + row n=2048 into Xs [b][s][d]
  k_unfold2<<<dim3(8192), blk, 0, stream>>>(ABout, g, uv, Xs);

  // 5) fused q/k/v projections (EPI=4), persistent 256 blocks x 3 tiles,
  //    sequential reps (R13-proven; cross-rep pipeline regressed in R15)
  gemm8<4, 0, 0, 0, 3><<<dim3(256), blk8, 0, stream>>>(
      Xs, WTcat, Qn, Kn, Vn, nullptr, bq, bk, bv, c_arr, nullptr,
      MTOT, 3 * DM, DM, 0, 0, 0);

  // 6) fused logits + head-softmax   7) attend+fold + buildM2 (merged)
  k_logsoft<<<dim3(MTOT / 16), blk, 0, stream>>>(Qn, Kn, wsm);
  k_attfoldM2<<<dim3(33 + 38, DM / 64, NB), blk, 0, stream>>>(Vn, wsm, A2t, cos_tab, Mc2);

  // 8) att_time_half = Mc2 @ A2 — 128^2 tiles for occupancy (576 wg, 2 blk/CU)
  dim3 ghalf(DM / 128, MH / 128, NB);
  gemm4<<<ghalf, blk, 0, stream>>>(Mc2, A2t, att_half,
                                   MH, DM, KH, (long)DM * KH, (long)MH * DM);

  // 9) out = att_time @ Wo + bo + x
  dim3 gproj(DM / 256, MTOT / 256, 1);
  gemm8<2, 1><<<gproj, blk8, 0, stream>>>(att_half, WoT, nullptr, nullptr, nullptr, out,
                                          bo, nullptr, nullptr, nullptr, x,
                                          MTOT, DM, DM, 0, 0, 0);
}